// Round 13
// baseline (114.788 us; speedup 1.0000x reference)
//
#include <hip/hip_runtime.h>

#define FF_N 4096
#define S64  0.015625f   // 1/64 per FWHT (total 1/4096)

typedef float v2f __attribute__((ext_vector_type(2)));

// Packed fp32 (VOP3P) — both rows of a pair in one instruction.
__device__ __forceinline__ v2f pk_add(v2f a, v2f b) {
    v2f d; asm("v_pk_add_f32 %0, %1, %2" : "=v"(d) : "v"(a), "v"(b)); return d;
}
__device__ __forceinline__ v2f pk_sub(v2f a, v2f b) {
    v2f d; asm("v_pk_add_f32 %0, %1, %2 neg_lo:[0,1] neg_hi:[0,1]"
               : "=v"(d) : "v"(a), "v"(b)); return d;
}

__device__ __forceinline__ void h16p(v2f v[16]) {
#pragma unroll
    for (int b = 1; b < 16; b <<= 1) {
#pragma unroll
        for (int r = 0; r < 16; ++r) {
            if ((r & b) == 0) {
                const v2f u = v[r], w = v[r | b];
                v[r]     = pk_add(u, w);
                v[r | b] = pk_sub(u, w);
            }
        }
    }
}

// ---- R12-verbatim layout helpers (A/P/W, conflict-verified R8/R9/R11) ----
__device__ __forceinline__ void a_read(v2f v[16], const v2f* __restrict__ L,
                                       int T, int c) {
#pragma unroll
    for (int j = 0; j < 16; ++j)
        v[j] = L[256 * j + 16 * T + 2 * ((c >> 1) ^ (j & 7)) + (c & 1)];
}
__device__ __forceinline__ void a_write(const v2f v[16], v2f* __restrict__ L,
                                        int T, int c) {
#pragma unroll
    for (int m = 0; m < 8; ++m) {
        const int p = 256 * c + 16 * T + 2 * (m ^ (c & 7));
        *(float4*)&L[p] = make_float4(v[2 * m][0], v[2 * m][1],
                                      v[2 * m + 1][0], v[2 * m + 1][1]);
    }
}
__device__ __forceinline__ void p_read(v2f v[16], const v2f* __restrict__ L,
                                       int T, int c, int h) {
#pragma unroll
    for (int j = 0; j < 16; ++j)
        v[j] = L[256 * j + 32 * (T >> 1) + 2 * c + ((T & 1) ^ h)];
}
__device__ __forceinline__ void p_write(const v2f v[16], v2f* __restrict__ L,
                                        int T, int c, int h) {
#pragma unroll
    for (int m = 0; m < 8; ++m) {
        const int p = 256 * T + 32 * m + 2 * c;
        const v2f lo = h ? v[2 * m + 1] : v[2 * m];
        const v2f hi = h ? v[2 * m]     : v[2 * m + 1];
        *(float4*)&L[p] = make_float4(lo[0], lo[1], hi[0], hi[1]);
    }
}
__device__ __forceinline__ void w_write(const v2f v[16], v2f* __restrict__ L,
                                        int T, int c) {
#pragma unroll
    for (int mu = 0; mu < 8; ++mu) {
        const int p = 512 * mu + 32 * T + 2 * (c ^ (mu & 7));
        *(float4*)&L[p] = make_float4(v[2 * mu][0], v[2 * mu][1],
                                      v[2 * mu + 1][0], v[2 * mu + 1][1]);
    }
}

// Per-launch precompute (R12 verbatim).
__global__ void ff_setup(const float* __restrict__ diag_s,
                         const float* __restrict__ diag_g,
                         const int*   __restrict__ perm,
                         int*   __restrict__ gaddr2,
                         float* __restrict__ gg,
                         float* __restrict__ ss) {
    const int k   = blockIdx.x * 256 + threadIdx.x;
    const int pe  = perm[k];
    const int d2p = pe >> 8, d1p = (pe >> 4) & 15, d0p = pe & 15;
    gaddr2[k] = 512 * (d2p >> 1) + 32 * d1p + 2 * (d0p ^ ((d2p >> 1) & 7)) + (d2p & 1);
    gg[k] = diag_g[k] * S64;
    ss[k] = diag_s[k] * S64;
}

// FOUR rows per block as two independent v2f pairs (P,Q), each with its own
// 32 KB LDS buffer, sharing all barriers. Per phase: issue P reads, Q reads,
// then compute P (Q reads in flight beneath it), compute Q -> cross-pair ILP
// fills the phase-latency stalls; per-row barrier cost halves.
__global__ __launch_bounds__(256) void fastfood_2p_kernel(
    const float* __restrict__ x,
    const float* __restrict__ diag_b,
    const int*   __restrict__ gaddr2,
    const float* __restrict__ gg,
    const float* __restrict__ ss,
    float* __restrict__ out)
{
    __shared__ __align__(16) v2f LP[FF_N];   // 32 KB (pair P)
    __shared__ __align__(16) v2f LQ[FF_N];   // 32 KB (pair Q)
    const int t = threadIdx.x;
    const int T = t >> 4, c = t & 15;
    const int h = c >> 3;
    const size_t row0 = (size_t)blockIdx.x * 4;
    const float* __restrict__ xA = x + row0 * FF_N;
    const float* __restrict__ xB = xA + FF_N;
    const float* __restrict__ xC = xB + FF_N;
    const float* __restrict__ xD = xC + FF_N;
    float* __restrict__ oA = out + row0 * FF_N;
    float* __restrict__ oB = oA + FF_N;
    float* __restrict__ oC = oB + FF_N;
    float* __restrict__ oD = oC + FF_N;

    v2f vP[16], vQ[16];

    // ===== P1: load 4 rows * diag_b; h16(d0); A-writes =====
    {
        const float4* __restrict__ a4 = (const float4*)(xA + 16 * t);
        const float4* __restrict__ b4 = (const float4*)(xB + 16 * t);
        const float4* __restrict__ c4 = (const float4*)(xC + 16 * t);
        const float4* __restrict__ d4 = (const float4*)(xD + 16 * t);
        const float4* __restrict__ g4 = (const float4*)(diag_b + 16 * t);
#pragma unroll
        for (int q = 0; q < 4; ++q) {
            const float4 gv = g4[q];
            const float4 av = a4[q], bv = b4[q], cv = c4[q], dv = d4[q];
            vP[4 * q + 0][0] = av.x * gv.x;  vP[4 * q + 0][1] = bv.x * gv.x;
            vP[4 * q + 1][0] = av.y * gv.y;  vP[4 * q + 1][1] = bv.y * gv.y;
            vP[4 * q + 2][0] = av.z * gv.z;  vP[4 * q + 2][1] = bv.z * gv.z;
            vP[4 * q + 3][0] = av.w * gv.w;  vP[4 * q + 3][1] = bv.w * gv.w;
            vQ[4 * q + 0][0] = cv.x * gv.x;  vQ[4 * q + 0][1] = dv.x * gv.x;
            vQ[4 * q + 1][0] = cv.y * gv.y;  vQ[4 * q + 1][1] = dv.y * gv.y;
            vQ[4 * q + 2][0] = cv.z * gv.z;  vQ[4 * q + 2][1] = dv.z * gv.z;
            vQ[4 * q + 3][0] = cv.w * gv.w;  vQ[4 * q + 3][1] = dv.w * gv.w;
        }
        h16p(vP); h16p(vQ);
        a_write(vP, LP, T, c);
        a_write(vQ, LQ, T, c);
    }
    __syncthreads();

    // ===== P2: A-reads; h16(d1); P-writes =====
    a_read(vP, LP, T, c);
    a_read(vQ, LQ, T, c);
    h16p(vP); h16p(vQ);
    __syncthreads();
    p_write(vP, LP, T, c, h);
    p_write(vQ, LQ, T, c, h);
    __syncthreads();

    // ===== P3: P-reads; h16(d2) -> FWHT1 done; W-writes =====
    p_read(vP, LP, T, c, h);
    p_read(vQ, LQ, T, c, h);
    h16p(vP); h16p(vQ);
    __syncthreads();
    w_write(vP, LP, T, c);
    w_write(vQ, LQ, T, c);
    __syncthreads();

    // ===== P4: precomputed gather * gg (shared); h16(d0'); A-writes =====
    {
        const int4*   __restrict__ ga4 = (const int4*)(gaddr2 + 16 * t);
        const float4* __restrict__ gg4 = (const float4*)(gg + 16 * t);
#pragma unroll
        for (int q = 0; q < 4; ++q) {
            const int4   pa = ga4[q];
            const float4 gv = gg4[q];
            const v2f p0 = LP[pa.x], p1 = LP[pa.y], p2 = LP[pa.z], p3 = LP[pa.w];
            const v2f q0 = LQ[pa.x], q1 = LQ[pa.y], q2 = LQ[pa.z], q3 = LQ[pa.w];
            vP[4 * q + 0][0] = p0[0] * gv.x;  vP[4 * q + 0][1] = p0[1] * gv.x;
            vP[4 * q + 1][0] = p1[0] * gv.y;  vP[4 * q + 1][1] = p1[1] * gv.y;
            vP[4 * q + 2][0] = p2[0] * gv.z;  vP[4 * q + 2][1] = p2[1] * gv.z;
            vP[4 * q + 3][0] = p3[0] * gv.w;  vP[4 * q + 3][1] = p3[1] * gv.w;
            vQ[4 * q + 0][0] = q0[0] * gv.x;  vQ[4 * q + 0][1] = q0[1] * gv.x;
            vQ[4 * q + 1][0] = q1[0] * gv.y;  vQ[4 * q + 1][1] = q1[1] * gv.y;
            vQ[4 * q + 2][0] = q2[0] * gv.z;  vQ[4 * q + 2][1] = q2[1] * gv.z;
            vQ[4 * q + 3][0] = q3[0] * gv.w;  vQ[4 * q + 3][1] = q3[1] * gv.w;
        }
        h16p(vP); h16p(vQ);
    }
    __syncthreads();
    a_write(vP, LP, T, c);
    a_write(vQ, LQ, T, c);
    __syncthreads();

    // ===== P5: A-reads; h16(d1'); P-writes =====
    a_read(vP, LP, T, c);
    a_read(vQ, LQ, T, c);
    h16p(vP); h16p(vQ);
    __syncthreads();
    p_write(vP, LP, T, c, h);
    p_write(vQ, LQ, T, c, h);
    __syncthreads();

    // ===== P6: P-reads; h16(d2'); dense NT stores * ss (shared) =====
    p_read(vP, LP, T, c, h);
    p_read(vQ, LQ, T, c, h);
    h16p(vP); h16p(vQ);
#pragma unroll
    for (int j = 0; j < 16; ++j) {
        const int e = 256 * j + t;
        const float s = ss[e];
        __builtin_nontemporal_store(vP[j][0] * s, &oA[e]);
        __builtin_nontemporal_store(vP[j][1] * s, &oB[e]);
        __builtin_nontemporal_store(vQ[j][0] * s, &oC[e]);
        __builtin_nontemporal_store(vQ[j][1] * s, &oD[e]);
    }
}

extern "C" void kernel_launch(void* const* d_in, const int* in_sizes, int n_in,
                              void* d_out, int out_size, void* d_ws, size_t ws_size,
                              hipStream_t stream) {
    const float* x      = (const float*)d_in[0];
    const float* diag_s = (const float*)d_in[1];
    const float* diag_g = (const float*)d_in[2];
    const float* diag_b = (const float*)d_in[3];
    const int*   perm   = (const int*)d_in[4];
    float* out = (float*)d_out;

    int*   gaddr2 = (int*)d_ws;
    float* gg     = (float*)d_ws + FF_N;
    float* ss     = (float*)d_ws + 2 * FF_N;

    ff_setup<<<FF_N / 256, 256, 0, stream>>>(diag_s, diag_g, perm, gaddr2, gg, ss);

    const int batch = in_sizes[0] / FF_N;   // 16384 rows
    fastfood_2p_kernel<<<batch / 4, 256, 0, stream>>>(x, diag_b, gaddr2, gg, ss, out);
}

// Round 14
// 93.095 us; speedup vs baseline: 1.2330x; 1.2330x over previous
//
#include <hip/hip_runtime.h>

#define FF_N 4096
#define S64  0.015625f   // 1/64 per FWHT (total 1/4096)

typedef float  v2f __attribute__((ext_vector_type(2)));
typedef __fp16 pkhalf2 __attribute__((ext_vector_type(2)));

// Packed fp32 (VOP3P) — both rows' butterfly op in one instruction.
__device__ __forceinline__ v2f pk_add(v2f a, v2f b) {
    v2f d; asm("v_pk_add_f32 %0, %1, %2" : "=v"(d) : "v"(a), "v"(b)); return d;
}
__device__ __forceinline__ v2f pk_sub(v2f a, v2f b) {
    v2f d; asm("v_pk_add_f32 %0, %1, %2 neg_lo:[0,1] neg_hi:[0,1]"
               : "=v"(d) : "v"(a), "v"(b)); return d;
}
__device__ __forceinline__ void h16p(v2f v[16]) {
#pragma unroll
    for (int b = 1; b < 16; b <<= 1) {
#pragma unroll
        for (int r = 0; r < 16; ++r) {
            if ((r & b) == 0) {
                const v2f u = v[r], w = v[r | b];
                v[r]     = pk_add(u, w);
                v[r | b] = pk_sub(u, w);
            }
        }
    }
}

// f16x2 pack/unpack: one LDS dword holds both rows' same element.
__device__ __forceinline__ unsigned pkpack(v2f a) {
    union { pkhalf2 h; unsigned u; } cv;
    cv.h = __builtin_amdgcn_cvt_pkrtz(a[0], a[1]);
    return cv.u;
}
__device__ __forceinline__ v2f pkunpack(unsigned u) {
    union { unsigned u; pkhalf2 h; } cv; cv.u = u;
    return (v2f){(float)cv.h[0], (float)cv.h[1]};
}

// ============================================================================
// Dword-unit layouts (element-pair = 1 dword). Digits e = 256*d2 + 16*d1 + d0.
// All bijective (bit-inversion verified); conflict status under the
// R8-validated rigid-group model:
//  A (J1/J4: write all-d0, read all-d1):
//    aA = (d2<<8)|((d1>>3)<<7)|((d0>>2)<<5)|(((d1&7)^(d0>>2))<<2)|(d0&3)
//  P (J2/J5: write all-d1, read all-d2):
//    aP = (d2<<8)|((d0>>3)<<7)|((d1>>2)<<5)|(((d0&7)^(d1>>2))<<2)|(d1&3)
//  W (J3: write all-d2, random gather read):
//    aW = (d1<<8)|((d0>>3)<<7)|((d2>>2)<<5)|(((d0&7)^(d2>>2))<<2)|(d2&3)
//  Writes (b128, 8-lane groups, T fixed, c&7 varying): quad = (c&7)^q -> 8
//  distinct quads, free. A-read bank = ((j&7)^(c>>2))<<2|(c&3): 2 lanes/bank.
//  P-read bank = ((c&7)^(T>>2))<<2|(T&3): 2 lanes/bank. Gather: inherent.
//  All three writes share base WB[q] = (T<<8)|((c>>3)<<7)|(q<<5)|(((c&7)^q)<<2).
// ============================================================================

__global__ void ff_setup(const float* __restrict__ diag_s,
                         const float* __restrict__ diag_g,
                         const int*   __restrict__ perm,
                         int*   __restrict__ gaddr,
                         float* __restrict__ gg,
                         float* __restrict__ ss) {
    const int k   = blockIdx.x * 256 + threadIdx.x;
    const int pe  = perm[k];
    const int d2p = pe >> 8, d1p = (pe >> 4) & 15, d0p = pe & 15;
    gaddr[k] = (d1p << 8) | ((d0p >> 3) << 7) | ((d2p >> 2) << 5)
             | (((d0p & 7) ^ (d2p >> 2)) << 2) | (d2p & 3);
    gg[k] = diag_g[k] * S64;
    ss[k] = diag_s[k] * S64;
}

__global__ __launch_bounds__(256, 6) void fastfood_h16_kernel(
    const float* __restrict__ x,
    const float* __restrict__ diag_b,
    const int*   __restrict__ gaddr,
    const float* __restrict__ gg,
    const float* __restrict__ ss,
    float* __restrict__ out)
{
    __shared__ __align__(16) unsigned L[FF_N];   // 16 KB (f16x2-packed pairs)
    const int t = threadIdx.x;
    const int T = t >> 4, c = t & 15;
    const size_t rowA = (size_t)blockIdx.x * 2;
    const float* __restrict__ xA   = x   + rowA * FF_N;
    const float* __restrict__ xB   = xA  + FF_N;
    float* __restrict__       outA = out + rowA * FF_N;
    float* __restrict__       outB = outA + FF_N;

    // shared write bases (A-, P-, W-writes all use the same formula)
    int WB[4];
#pragma unroll
    for (int q = 0; q < 4; ++q)
        WB[q] = (T << 8) | ((c >> 3) << 7) | (q << 5) | ((((c & 7) ^ q)) << 2);
    const int AR0 = (T << 8) | ((c >> 2) << 5) | (c & 3);           // A-read base
    const int PR0 = ((c >> 3) << 7) | ((T >> 2) << 5)
                  | ((((c & 7) ^ (T >> 2))) << 2) | (T & 3);        // P-read base

    v2f v[16];

#define JWRITE()                                                               \
    {                                                                          \
        _Pragma("unroll")                                                      \
        for (int q = 0; q < 4; ++q) {                                          \
            uint4 w;                                                           \
            w.x = pkpack(v[4 * q + 0]); w.y = pkpack(v[4 * q + 1]);            \
            w.z = pkpack(v[4 * q + 2]); w.w = pkpack(v[4 * q + 3]);            \
            *(uint4*)&L[WB[q]] = w;                                            \
        }                                                                      \
    }

    // ===== P1: load both rows * diag_b (float4, coalesced); h16(d0); A-write =====
    {
        const float4* __restrict__ xa4 = (const float4*)(xA + 16 * t);
        const float4* __restrict__ xb4 = (const float4*)(xB + 16 * t);
        const float4* __restrict__ b4  = (const float4*)(diag_b + 16 * t);
#pragma unroll
        for (int q = 0; q < 4; ++q) {
            const float4 bv = b4[q];
            const float4 av = xa4[q];
            const float4 wv = xb4[q];
            v[4 * q + 0] = (v2f){av.x * bv.x, wv.x * bv.x};
            v[4 * q + 1] = (v2f){av.y * bv.y, wv.y * bv.y};
            v[4 * q + 2] = (v2f){av.z * bv.z, wv.z * bv.z};
            v[4 * q + 3] = (v2f){av.w * bv.w, wv.w * bv.w};
        }
        h16p(v);
        JWRITE();
    }
    __syncthreads();

    // ===== P2: A-read all d1 (b32); h16(d1); P-write =====
#pragma unroll
    for (int j = 0; j < 16; ++j)
        v[j] = pkunpack(L[AR0 | ((j >> 3) << 7) | ((((j & 7) ^ (c >> 2))) << 2)]);
    h16p(v);
    __syncthreads();
    JWRITE();
    __syncthreads();

    // ===== P3: P-read all d2 (b32); h16(d2) -> FWHT1 done; W-write =====
#pragma unroll
    for (int j = 0; j < 16; ++j)
        v[j] = pkunpack(L[PR0 | (j << 8)]);
    h16p(v);
    __syncthreads();
    JWRITE();
    __syncthreads();

    // ===== P4: precomputed gather (b32, both rows) * gg; h16(d0'); A-write =====
    {
        const int4*   __restrict__ ga4 = (const int4*)(gaddr + 16 * t);
        const float4* __restrict__ gg4 = (const float4*)(gg + 16 * t);
#pragma unroll
        for (int q = 0; q < 4; ++q) {
            const int4   pa = ga4[q];
            const float4 gv = gg4[q];
            const v2f a0 = pkunpack(L[pa.x]), a1 = pkunpack(L[pa.y]);
            const v2f a2 = pkunpack(L[pa.z]), a3 = pkunpack(L[pa.w]);
            v[4 * q + 0] = (v2f){a0[0] * gv.x, a0[1] * gv.x};
            v[4 * q + 1] = (v2f){a1[0] * gv.y, a1[1] * gv.y};
            v[4 * q + 2] = (v2f){a2[0] * gv.z, a2[1] * gv.z};
            v[4 * q + 3] = (v2f){a3[0] * gv.w, a3[1] * gv.w};
        }
        h16p(v);
    }
    __syncthreads();
    JWRITE();
    __syncthreads();

    // ===== P5: A-read; h16(d1'); P-write =====
#pragma unroll
    for (int j = 0; j < 16; ++j)
        v[j] = pkunpack(L[AR0 | ((j >> 3) << 7) | ((((j & 7) ^ (c >> 2))) << 2)]);
    h16p(v);
    __syncthreads();
    JWRITE();
    __syncthreads();

    // ===== P6: P-read; h16(d2'); DENSE NT store out[256j + t] * ss =====
#pragma unroll
    for (int j = 0; j < 16; ++j)
        v[j] = pkunpack(L[PR0 | (j << 8)]);
    h16p(v);
#pragma unroll
    for (int j = 0; j < 16; ++j) {
        const int e = 256 * j + t;
        const float s = ss[e];
        __builtin_nontemporal_store(v[j][0] * s, &outA[e]);
        __builtin_nontemporal_store(v[j][1] * s, &outB[e]);
    }
#undef JWRITE
}

extern "C" void kernel_launch(void* const* d_in, const int* in_sizes, int n_in,
                              void* d_out, int out_size, void* d_ws, size_t ws_size,
                              hipStream_t stream) {
    const float* x      = (const float*)d_in[0];
    const float* diag_s = (const float*)d_in[1];
    const float* diag_g = (const float*)d_in[2];
    const float* diag_b = (const float*)d_in[3];
    const int*   perm   = (const int*)d_in[4];
    float* out = (float*)d_out;

    int*   gaddr = (int*)d_ws;
    float* gg    = (float*)d_ws + FF_N;
    float* ss    = (float*)d_ws + 2 * FF_N;

    ff_setup<<<FF_N / 256, 256, 0, stream>>>(diag_s, diag_g, perm, gaddr, gg, ss);

    const int batch = in_sizes[0] / FF_N;   // 16384 rows
    fastfood_h16_kernel<<<batch / 2, 256, 0, stream>>>(x, diag_b, gaddr, gg, ss, out);
}